// Round 14
// baseline (203.081 us; speedup 1.0000x reference)
//
#include <hip/hip_runtime.h>
#include <math.h>

#define HID   1024
#define OUTD  8192
#define NSUBJ 8
#define BATCH 64
#define TLEN  512

// ws layout (float offsets)
#define OFF_PP    0u           // pool partials: 16*64*1024 = 1048576
#define OFF_P1    1048576u     // mlp1 partials: 32*64*1024 = 2097152
#define OFF_P2    3145728u     // mlp2 partials: 32*64*1024
#define OFF_H     5242880u     // 64*1024
#define OFF_MUP   5308416u     // mu partials: 8*64*8192 = 4194304
#define OFF_LVP   9502720u     // lv partials: 4*64*8192 = 2097152

// ---------------- mean pool: partial sums over 32-t chunks (r4) ----------------
__global__ __launch_bounds__(256) void k_pool(const float* __restrict__ ctx,
                                              float* __restrict__ pp) {
    int b  = blockIdx.x;   // 64
    int tc = blockIdx.y;   // 16
    int hid = threadIdx.x * 4;
    const float* base = ctx + ((size_t)b * TLEN + (size_t)tc * 32) * HID + hid;
    float4 acc = make_float4(0.f, 0.f, 0.f, 0.f);
#pragma unroll 8
    for (int t = 0; t < 32; ++t) {
        float4 v = *(const float4*)(base + (size_t)t * HID);
        acc.x += v.x; acc.y += v.y; acc.z += v.z; acc.w += v.w;
    }
    *(float4*)(pp + ((size_t)tc * BATCH + b) * HID + hid) = acc;
}

// -------- MLP layer 1: fused pool-reduce (LDS x-tile) + GEMM partial (r4 exact) -----
__global__ __launch_bounds__(256) void k_mlp1(const float* __restrict__ pp,
                                              const float* __restrict__ w1,
                                              float* __restrict__ p1) {
    __shared__ float xs[32][34];
    int j  = blockIdx.x * 256 + threadIdx.x;  // 4 jchunks
    int k0 = blockIdx.y * 32;                 // 32 kchunks
    int b0 = blockIdx.z * 32;                 // 2 bgroups
    {
        int bb = threadIdx.x >> 3;
        int kk = (threadIdx.x & 7) * 4;
        float4 s = make_float4(0.f, 0.f, 0.f, 0.f);
#pragma unroll
        for (int tc = 0; tc < 16; ++tc) {
            float4 v = *(const float4*)(pp + (size_t)tc * 65536 + (b0 + bb) * 1024 + k0 + kk);
            s.x += v.x; s.y += v.y; s.z += v.z; s.w += v.w;
        }
        const float inv = 1.0f / 512.0f;
        xs[bb][kk]     = s.x * inv;
        xs[bb][kk + 1] = s.y * inv;
        xs[bb][kk + 2] = s.z * inv;
        xs[bb][kk + 3] = s.w * inv;
    }
    __syncthreads();
    float acc[32];
#pragma unroll
    for (int i = 0; i < 32; ++i) acc[i] = 0.f;
    for (int kk = 0; kk < 32; kk += 2) {
        float wa = w1[(size_t)(k0 + kk) * HID + j];
        float wb = w1[(size_t)(k0 + kk + 1) * HID + j];
#pragma unroll
        for (int i = 0; i < 32; ++i) {
            acc[i] = fmaf(xs[i][kk], wa, acc[i]);
            acc[i] = fmaf(xs[i][kk + 1], wb, acc[i]);
        }
    }
    float* dst = p1 + (size_t)blockIdx.y * 65536;
#pragma unroll
    for (int i = 0; i < 32; ++i) dst[(b0 + i) * 1024 + j] = acc[i];
}

// -------- MLP layer 2: fused reduce+bias+exact-GELU + GEMM partial (r4 exact) -------
__global__ __launch_bounds__(256) void k_mlp2(const float* __restrict__ p1,
                                              const float* __restrict__ b1,
                                              const float* __restrict__ w2,
                                              float* __restrict__ p2) {
    __shared__ float xs[32][34];
    int j  = blockIdx.x * 256 + threadIdx.x;
    int k0 = blockIdx.y * 32;
    int b0 = blockIdx.z * 32;
    {
        int bb = threadIdx.x >> 3;
        int kk = (threadIdx.x & 7) * 4;
        float4 s = make_float4(0.f, 0.f, 0.f, 0.f);
#pragma unroll
        for (int kc = 0; kc < 32; ++kc) {
            float4 v = *(const float4*)(p1 + (size_t)kc * 65536 + (b0 + bb) * 1024 + k0 + kk);
            s.x += v.x; s.y += v.y; s.z += v.z; s.w += v.w;
        }
        float4 bbv = *(const float4*)(b1 + k0 + kk);
        s.x += bbv.x; s.y += bbv.y; s.z += bbv.z; s.w += bbv.w;
        const float r = 0.70710678118654752f;
        xs[bb][kk]     = 0.5f * s.x * (1.0f + erff(s.x * r));
        xs[bb][kk + 1] = 0.5f * s.y * (1.0f + erff(s.y * r));
        xs[bb][kk + 2] = 0.5f * s.z * (1.0f + erff(s.z * r));
        xs[bb][kk + 3] = 0.5f * s.w * (1.0f + erff(s.w * r));
    }
    __syncthreads();
    float acc[32];
#pragma unroll
    for (int i = 0; i < 32; ++i) acc[i] = 0.f;
    for (int kk = 0; kk < 32; kk += 2) {
        float wa = w2[(size_t)(k0 + kk) * HID + j];
        float wb = w2[(size_t)(k0 + kk + 1) * HID + j];
#pragma unroll
        for (int i = 0; i < 32; ++i) {
            acc[i] = fmaf(xs[i][kk], wa, acc[i]);
            acc[i] = fmaf(xs[i][kk + 1], wb, acc[i]);
        }
    }
    float* dst = p2 + (size_t)blockIdx.y * 65536;
#pragma unroll
    for (int i = 0; i < 32; ++i) dst[(b0 + i) * 1024 + j] = acc[i];
}

// ---------------- reduce 32 partials + bias -> hbuf (r4) ----------------
__global__ __launch_bounds__(256) void k_red_bias(const float* __restrict__ p,
                                                  const float* __restrict__ bias,
                                                  float* __restrict__ out) {
    int i = (blockIdx.x * 256 + threadIdx.x) * 4;  // 64 blocks
    int j = i & (HID - 1);
    float4 s = make_float4(0.f, 0.f, 0.f, 0.f);
#pragma unroll
    for (int kc = 0; kc < 32; ++kc) {
        float4 v = *(const float4*)(p + (size_t)kc * 65536 + i);
        s.x += v.x; s.y += v.y; s.z += v.z; s.w += v.w;
    }
    float4 bb = *(const float4*)(bias + j);
    s.x += bb.x; s.y += bb.y; s.z += bb.z; s.w += bb.w;
    *(float4*)(out + i) = s;
}

// -------- head tile body: NS samples, KLEN k-range, wv prefetch (r4-proven) --------
template <int NS, int KLEN>
__device__ __forceinline__ void mu_tile(const float* __restrict__ hmat,
                                        const float* __restrict__ wbase,
                                        float* __restrict__ dst_kc,
                                        const int* bo, int n, int k0, int o) {
    float4 acc[NS];
#pragma unroll
    for (int i = 0; i < NS; ++i) acc[i] = make_float4(0.f, 0.f, 0.f, 0.f);
    float4 wv[4];
#pragma unroll
    for (int kk = 0; kk < 4; ++kk)
        wv[kk] = *(const float4*)(wbase + (size_t)(k0 + kk) * OUTD + o);
    for (int k = k0; k < k0 + KLEN; k += 4) {
        float4 hv[NS];
#pragma unroll
        for (int i = 0; i < NS; ++i)
            hv[i] = *(const float4*)(hmat + bo[i] * HID + k);
        int kn = (k + 4 < k0 + KLEN) ? (k + 4) : k0;  // last-iter reload, harmless
        float4 wn[4];
#pragma unroll
        for (int kk = 0; kk < 4; ++kk)
            wn[kk] = *(const float4*)(wbase + (size_t)(kn + kk) * OUTD + o);
#pragma unroll
        for (int kk = 0; kk < 4; ++kk) {
            float4 w = wv[kk];
#pragma unroll
            for (int i = 0; i < NS; ++i) {
                float h = (kk == 0) ? hv[i].x : (kk == 1) ? hv[i].y
                        : (kk == 2) ? hv[i].z : hv[i].w;
                acc[i].x = fmaf(h, w.x, acc[i].x);
                acc[i].y = fmaf(h, w.y, acc[i].y);
                acc[i].z = fmaf(h, w.z, acc[i].z);
                acc[i].w = fmaf(h, w.w, acc[i].w);
            }
        }
#pragma unroll
        for (int kk = 0; kk < 4; ++kk) wv[kk] = wn[kk];
    }
#pragma unroll
    for (int i = 0; i < NS; ++i)
        if (i < n) *(float4*)(dst_kc + (size_t)bo[i] * OUTD + o) = acc[i];
}

// ------ merged heads: blk<128 = lv FIRST (long blocks start early); rest = mu ------
__global__ __launch_bounds__(256) void k_head(const float* __restrict__ hbuf,
                                              const float* __restrict__ subj_w,
                                              const float* __restrict__ lv_w,
                                              const int* __restrict__ sid,
                                              float* __restrict__ mup,
                                              float* __restrict__ lvp) {
    int blk = blockIdx.x;
    int tid = threadIdx.x;
    if (blk < 128) {
        // ---- lv partial: u in [0,128): och = u&31 (o=256 f), kc = u>>5 (k=256) ----
        int u   = blk;
        int wid = tid >> 6;
        int lane = tid & 63;
        int o  = (u & 31) * 256 + lane * 4;
        int k0 = (u >> 5) * 256;
        int s0 = wid * 16;
        int bo[16];
#pragma unroll
        for (int i = 0; i < 16; ++i) bo[i] = s0 + i;
        float* lvp_kc = lvp + (size_t)(u >> 5) * BATCH * OUTD;
        mu_tile<16, 256>(hbuf, lv_w, lvp_kc, bo, 16, k0, o);
    } else {
        // ---- mu partial: v = blk-128; och = v&7, kc = (v>>3)&7, s = v>>6 ----
        int v  = blk - 128;
        int o  = (v & 7) * 1024 + tid * 4;
        int k0 = ((v >> 3) & 7) * 128;
        int s  = v >> 6;
        int lane = tid & 63;
        int mysid = sid[lane];
        unsigned long long m = __ballot(mysid == s);
        int ns = __popcll(m);
        if (ns == 0) return;
        const float* wbase = subj_w + (size_t)s * HID * OUTD;
        float* mup_kc = mup + (size_t)((v >> 3) & 7) * BATCH * OUTD;
        unsigned long long mm = m;
        for (int base = 0; base < ns; base += 12) {
            int take = ns - base; if (take > 12) take = 12;
            int fb = (int)__builtin_ctzll(mm);
            int bo[12];
#pragma unroll
            for (int i = 0; i < 12; ++i) {
                bo[i] = (mm != 0ull) ? (int)__builtin_ctzll(mm) : fb;
                if (mm != 0ull) mm &= (mm - 1ull);
            }
            if (take <= 4)       mu_tile<4, 128>(hbuf, wbase, mup_kc, bo, take, k0, o);
            else if (take <= 8)  mu_tile<8, 128>(hbuf, wbase, mup_kc, bo, take, k0, o);
            else                 mu_tile<12, 128>(hbuf, wbase, mup_kc, bo, take, k0, o);
        }
    }
}

// ------- combine: 8 mu partials + 4 lv partials, biases, clip, sample --------------
__global__ __launch_bounds__(256) void k_combine(const float* __restrict__ mup,
                                                 const float* __restrict__ lvp,
                                                 const float* __restrict__ eps,
                                                 const float* __restrict__ subj_b,
                                                 const float* __restrict__ lv_b,
                                                 const int* __restrict__ sid,
                                                 float* __restrict__ out) {
    int idx = (blockIdx.x * 256 + threadIdx.x) * 4;  // over 524288
    int b = idx >> 13;
    int o = idx & (OUTD - 1);
    float4 m = make_float4(0.f, 0.f, 0.f, 0.f);
    float4 l = make_float4(0.f, 0.f, 0.f, 0.f);
#pragma unroll
    for (int kc = 0; kc < 8; ++kc) {
        float4 t = *(const float4*)(mup + (size_t)kc * 524288 + idx);
        m.x += t.x; m.y += t.y; m.z += t.z; m.w += t.w;
    }
#pragma unroll
    for (int kc = 0; kc < 4; ++kc) {
        float4 u = *(const float4*)(lvp + (size_t)kc * 524288 + idx);
        l.x += u.x; l.y += u.y; l.z += u.z; l.w += u.w;
    }
    int s = sid[b];
    float4 sb = *(const float4*)(subj_b + s * OUTD + o);
    float4 lb = *(const float4*)(lv_b + o);
    m.x += sb.x; m.y += sb.y; m.z += sb.z; m.w += sb.w;
    l.x = fminf(fmaxf(l.x + lb.x, -10.f), 2.f);
    l.y = fminf(fmaxf(l.y + lb.y, -10.f), 2.f);
    l.z = fminf(fmaxf(l.z + lb.z, -10.f), 2.f);
    l.w = fminf(fmaxf(l.w + lb.w, -10.f), 2.f);
    float4 e = *(const float4*)(eps + idx);
    float4 x0;
    x0.x = m.x + e.x * __expf(0.5f * l.x);
    x0.y = m.y + e.y * __expf(0.5f * l.y);
    x0.z = m.z + e.z * __expf(0.5f * l.z);
    x0.w = m.w + e.w * __expf(0.5f * l.w);
    *(float4*)(out + idx) = x0;
    *(float4*)(out + 524288 + idx) = m;
    *(float4*)(out + 1048576 + idx) = l;
}

extern "C" void kernel_launch(void* const* d_in, const int* in_sizes, int n_in,
                              void* d_out, int out_size, void* d_ws, size_t ws_size,
                              hipStream_t stream) {
    const float* ctx    = (const float*)d_in[0];
    const int*   sid    = (const int*)  d_in[1];
    const float* eps    = (const float*)d_in[2];
    const float* w1     = (const float*)d_in[3];
    const float* b1     = (const float*)d_in[4];
    const float* w2     = (const float*)d_in[5];
    const float* b2     = (const float*)d_in[6];
    const float* subj_w = (const float*)d_in[7];
    const float* subj_b = (const float*)d_in[8];
    const float* lv_w   = (const float*)d_in[9];
    const float* lv_b   = (const float*)d_in[10];
    float* out = (float*)d_out;

    float* ws   = (float*)d_ws;
    float* pp   = ws + OFF_PP;
    float* p1   = ws + OFF_P1;
    float* p2   = ws + OFF_P2;
    float* hbuf = ws + OFF_H;
    float* mup  = ws + OFF_MUP;
    float* lvp  = ws + OFF_LVP;

    k_pool<<<dim3(BATCH, 16), 256, 0, stream>>>(ctx, pp);
    k_mlp1<<<dim3(4, 32, 2), 256, 0, stream>>>(pp, w1, p1);
    k_mlp2<<<dim3(4, 32, 2), 256, 0, stream>>>(p1, b1, w2, p2);
    k_red_bias<<<64, 256, 0, stream>>>(p2, b2, hbuf);
    k_head<<<640, 256, 0, stream>>>(hbuf, subj_w, lv_w, sid, mup, lvp);
    k_combine<<<512, 256, 0, stream>>>(mup, lvp, eps, subj_b, lv_b, sid, out);
}

// Round 15
// 169.382 us; speedup vs baseline: 1.1990x; 1.1990x over previous
//
#include <hip/hip_runtime.h>
#include <math.h>

#define HID   1024
#define OUTD  8192
#define NSUBJ 8
#define BATCH 64
#define TLEN  512

// ws layout (float offsets)
#define OFF_PP    0u           // pool partials: 16*64*1024 = 1048576
#define OFF_P1    1048576u     // mlp1 partials: 32*64*1024 = 2097152
#define OFF_P2    3145728u     // mlp2 partials: 32*64*1024
#define OFF_H     5242880u     // 64*1024
#define OFF_MUP   5308416u     // mu partials: 8*64*8192 = 4194304
#define OFF_LVP   9502720u     // lv partials: 8*64*8192 = 4194304

// ---------------- mean pool: partial sums over 32-t chunks (r4) ----------------
__global__ __launch_bounds__(256) void k_pool(const float* __restrict__ ctx,
                                              float* __restrict__ pp) {
    int b  = blockIdx.x;   // 64
    int tc = blockIdx.y;   // 16
    int hid = threadIdx.x * 4;
    const float* base = ctx + ((size_t)b * TLEN + (size_t)tc * 32) * HID + hid;
    float4 acc = make_float4(0.f, 0.f, 0.f, 0.f);
#pragma unroll 8
    for (int t = 0; t < 32; ++t) {
        float4 v = *(const float4*)(base + (size_t)t * HID);
        acc.x += v.x; acc.y += v.y; acc.z += v.z; acc.w += v.w;
    }
    *(float4*)(pp + ((size_t)tc * BATCH + b) * HID + hid) = acc;
}

// -------- MLP layer 1: fused pool-reduce (LDS x-tile) + GEMM partial (r4 exact) -----
__global__ __launch_bounds__(256) void k_mlp1(const float* __restrict__ pp,
                                              const float* __restrict__ w1,
                                              float* __restrict__ p1) {
    __shared__ float xs[32][34];
    int j  = blockIdx.x * 256 + threadIdx.x;  // 4 jchunks
    int k0 = blockIdx.y * 32;                 // 32 kchunks
    int b0 = blockIdx.z * 32;                 // 2 bgroups
    {
        int bb = threadIdx.x >> 3;
        int kk = (threadIdx.x & 7) * 4;
        float4 s = make_float4(0.f, 0.f, 0.f, 0.f);
#pragma unroll
        for (int tc = 0; tc < 16; ++tc) {
            float4 v = *(const float4*)(pp + (size_t)tc * 65536 + (b0 + bb) * 1024 + k0 + kk);
            s.x += v.x; s.y += v.y; s.z += v.z; s.w += v.w;
        }
        const float inv = 1.0f / 512.0f;
        xs[bb][kk]     = s.x * inv;
        xs[bb][kk + 1] = s.y * inv;
        xs[bb][kk + 2] = s.z * inv;
        xs[bb][kk + 3] = s.w * inv;
    }
    __syncthreads();
    float acc[32];
#pragma unroll
    for (int i = 0; i < 32; ++i) acc[i] = 0.f;
    for (int kk = 0; kk < 32; kk += 2) {
        float wa = w1[(size_t)(k0 + kk) * HID + j];
        float wb = w1[(size_t)(k0 + kk + 1) * HID + j];
#pragma unroll
        for (int i = 0; i < 32; ++i) {
            acc[i] = fmaf(xs[i][kk], wa, acc[i]);
            acc[i] = fmaf(xs[i][kk + 1], wb, acc[i]);
        }
    }
    float* dst = p1 + (size_t)blockIdx.y * 65536;
#pragma unroll
    for (int i = 0; i < 32; ++i) dst[(b0 + i) * 1024 + j] = acc[i];
}

// -------- MLP layer 2: fused reduce+bias+exact-GELU + GEMM partial (r4 exact) -------
__global__ __launch_bounds__(256) void k_mlp2(const float* __restrict__ p1,
                                              const float* __restrict__ b1,
                                              const float* __restrict__ w2,
                                              float* __restrict__ p2) {
    __shared__ float xs[32][34];
    int j  = blockIdx.x * 256 + threadIdx.x;
    int k0 = blockIdx.y * 32;
    int b0 = blockIdx.z * 32;
    {
        int bb = threadIdx.x >> 3;
        int kk = (threadIdx.x & 7) * 4;
        float4 s = make_float4(0.f, 0.f, 0.f, 0.f);
#pragma unroll
        for (int kc = 0; kc < 32; ++kc) {
            float4 v = *(const float4*)(p1 + (size_t)kc * 65536 + (b0 + bb) * 1024 + k0 + kk);
            s.x += v.x; s.y += v.y; s.z += v.z; s.w += v.w;
        }
        float4 bbv = *(const float4*)(b1 + k0 + kk);
        s.x += bbv.x; s.y += bbv.y; s.z += bbv.z; s.w += bbv.w;
        const float r = 0.70710678118654752f;
        xs[bb][kk]     = 0.5f * s.x * (1.0f + erff(s.x * r));
        xs[bb][kk + 1] = 0.5f * s.y * (1.0f + erff(s.y * r));
        xs[bb][kk + 2] = 0.5f * s.z * (1.0f + erff(s.z * r));
        xs[bb][kk + 3] = 0.5f * s.w * (1.0f + erff(s.w * r));
    }
    __syncthreads();
    float acc[32];
#pragma unroll
    for (int i = 0; i < 32; ++i) acc[i] = 0.f;
    for (int kk = 0; kk < 32; kk += 2) {
        float wa = w2[(size_t)(k0 + kk) * HID + j];
        float wb = w2[(size_t)(k0 + kk + 1) * HID + j];
#pragma unroll
        for (int i = 0; i < 32; ++i) {
            acc[i] = fmaf(xs[i][kk], wa, acc[i]);
            acc[i] = fmaf(xs[i][kk + 1], wb, acc[i]);
        }
    }
    float* dst = p2 + (size_t)blockIdx.y * 65536;
#pragma unroll
    for (int i = 0; i < 32; ++i) dst[(b0 + i) * 1024 + j] = acc[i];
}

// ---------------- reduce 32 partials + bias -> hbuf (r4) ----------------
__global__ __launch_bounds__(256) void k_red_bias(const float* __restrict__ p,
                                                  const float* __restrict__ bias,
                                                  float* __restrict__ out) {
    int i = (blockIdx.x * 256 + threadIdx.x) * 4;  // 64 blocks
    int j = i & (HID - 1);
    float4 s = make_float4(0.f, 0.f, 0.f, 0.f);
#pragma unroll
    for (int kc = 0; kc < 32; ++kc) {
        float4 v = *(const float4*)(p + (size_t)kc * 65536 + i);
        s.x += v.x; s.y += v.y; s.z += v.z; s.w += v.w;
    }
    float4 bb = *(const float4*)(bias + j);
    s.x += bb.x; s.y += bb.y; s.z += bb.z; s.w += bb.w;
    *(float4*)(out + i) = s;
}

// -------- head tile body: NS samples, KLEN k-range, wv prefetch (r4-proven) --------
template <int NS, int KLEN>
__device__ __forceinline__ void mu_tile(const float* __restrict__ hmat,
                                        const float* __restrict__ wbase,
                                        float* __restrict__ dst_kc,
                                        const int* bo, int n, int k0, int o) {
    float4 acc[NS];
#pragma unroll
    for (int i = 0; i < NS; ++i) acc[i] = make_float4(0.f, 0.f, 0.f, 0.f);
    float4 wv[4];
#pragma unroll
    for (int kk = 0; kk < 4; ++kk)
        wv[kk] = *(const float4*)(wbase + (size_t)(k0 + kk) * OUTD + o);
    for (int k = k0; k < k0 + KLEN; k += 4) {
        float4 hv[NS];
#pragma unroll
        for (int i = 0; i < NS; ++i)
            hv[i] = *(const float4*)(hmat + bo[i] * HID + k);
        int kn = (k + 4 < k0 + KLEN) ? (k + 4) : k0;  // last-iter reload, harmless
        float4 wn[4];
#pragma unroll
        for (int kk = 0; kk < 4; ++kk)
            wn[kk] = *(const float4*)(wbase + (size_t)(kn + kk) * OUTD + o);
#pragma unroll
        for (int kk = 0; kk < 4; ++kk) {
            float4 w = wv[kk];
#pragma unroll
            for (int i = 0; i < NS; ++i) {
                float h = (kk == 0) ? hv[i].x : (kk == 1) ? hv[i].y
                        : (kk == 2) ? hv[i].z : hv[i].w;
                acc[i].x = fmaf(h, w.x, acc[i].x);
                acc[i].y = fmaf(h, w.y, acc[i].y);
                acc[i].z = fmaf(h, w.z, acc[i].z);
                acc[i].w = fmaf(h, w.w, acc[i].w);
            }
        }
#pragma unroll
        for (int kk = 0; kk < 4; ++kk) wv[kk] = wn[kk];
    }
#pragma unroll
    for (int i = 0; i < NS; ++i)
        if (i < n) *(float4*)(dst_kc + (size_t)bo[i] * OUTD + o) = acc[i];
}

// ------ merged heads: blk<512 = mu (r4-exact); blk in [512,768) = lv (ksplit 8) -----
__global__ __launch_bounds__(256) void k_head(const float* __restrict__ hbuf,
                                              const float* __restrict__ subj_w,
                                              const float* __restrict__ lv_w,
                                              const int* __restrict__ sid,
                                              float* __restrict__ mup,
                                              float* __restrict__ lvp) {
    int blk = blockIdx.x;
    int tid = threadIdx.x;
    if (blk < 512) {
        // ---- mu partial: och = blk&7, kc = (blk>>3)&7, s = blk>>6 ----
        int o  = (blk & 7) * 1024 + tid * 4;
        int k0 = ((blk >> 3) & 7) * 128;
        int s  = blk >> 6;
        int lane = tid & 63;
        int mysid = sid[lane];
        unsigned long long m = __ballot(mysid == s);
        int ns = __popcll(m);
        if (ns == 0) return;
        const float* wbase = subj_w + (size_t)s * HID * OUTD;
        float* mup_kc = mup + (size_t)((blk >> 3) & 7) * BATCH * OUTD;
        unsigned long long mm = m;
        for (int base = 0; base < ns; base += 12) {
            int take = ns - base; if (take > 12) take = 12;
            int fb = (int)__builtin_ctzll(mm);
            int bo[12];
#pragma unroll
            for (int i = 0; i < 12; ++i) {
                bo[i] = (mm != 0ull) ? (int)__builtin_ctzll(mm) : fb;
                if (mm != 0ull) mm &= (mm - 1ull);
            }
            if (take <= 4)       mu_tile<4, 128>(hbuf, wbase, mup_kc, bo, take, k0, o);
            else if (take <= 8)  mu_tile<8, 128>(hbuf, wbase, mup_kc, bo, take, k0, o);
            else                 mu_tile<12, 128>(hbuf, wbase, mup_kc, bo, take, k0, o);
        }
    } else {
        // ---- lv partial: u in [0,256): och = u&31 (o=256 f), kc = u>>5 (k=128) ----
        // 4 waves x 16 samples each; weight tile (128k x 256o = 128 KB) read once.
        int u   = blk - 512;
        int wid = tid >> 6;
        int lane = tid & 63;
        int o  = (u & 31) * 256 + lane * 4;
        int k0 = (u >> 5) * 128;
        int s0 = wid * 16;
        int bo[16];
#pragma unroll
        for (int i = 0; i < 16; ++i) bo[i] = s0 + i;
        float* lvp_kc = lvp + (size_t)(u >> 5) * BATCH * OUTD;
        mu_tile<16, 128>(hbuf, lv_w, lvp_kc, bo, 16, k0, o);
    }
}

// ------- combine: 8 mu partials + 8 lv partials, biases, clip, sample --------------
__global__ __launch_bounds__(256) void k_combine(const float* __restrict__ mup,
                                                 const float* __restrict__ lvp,
                                                 const float* __restrict__ eps,
                                                 const float* __restrict__ subj_b,
                                                 const float* __restrict__ lv_b,
                                                 const int* __restrict__ sid,
                                                 float* __restrict__ out) {
    int idx = (blockIdx.x * 256 + threadIdx.x) * 4;  // over 524288
    int b = idx >> 13;
    int o = idx & (OUTD - 1);
    float4 m = make_float4(0.f, 0.f, 0.f, 0.f);
    float4 l = make_float4(0.f, 0.f, 0.f, 0.f);
#pragma unroll
    for (int kc = 0; kc < 8; ++kc) {
        float4 t = *(const float4*)(mup + (size_t)kc * 524288 + idx);
        m.x += t.x; m.y += t.y; m.z += t.z; m.w += t.w;
        float4 u = *(const float4*)(lvp + (size_t)kc * 524288 + idx);
        l.x += u.x; l.y += u.y; l.z += u.z; l.w += u.w;
    }
    int s = sid[b];
    float4 sb = *(const float4*)(subj_b + s * OUTD + o);
    float4 lb = *(const float4*)(lv_b + o);
    m.x += sb.x; m.y += sb.y; m.z += sb.z; m.w += sb.w;
    l.x = fminf(fmaxf(l.x + lb.x, -10.f), 2.f);
    l.y = fminf(fmaxf(l.y + lb.y, -10.f), 2.f);
    l.z = fminf(fmaxf(l.z + lb.z, -10.f), 2.f);
    l.w = fminf(fmaxf(l.w + lb.w, -10.f), 2.f);
    float4 e = *(const float4*)(eps + idx);
    float4 x0;
    x0.x = m.x + e.x * __expf(0.5f * l.x);
    x0.y = m.y + e.y * __expf(0.5f * l.y);
    x0.z = m.z + e.z * __expf(0.5f * l.z);
    x0.w = m.w + e.w * __expf(0.5f * l.w);
    *(float4*)(out + idx) = x0;
    *(float4*)(out + 524288 + idx) = m;
    *(float4*)(out + 1048576 + idx) = l;
}

extern "C" void kernel_launch(void* const* d_in, const int* in_sizes, int n_in,
                              void* d_out, int out_size, void* d_ws, size_t ws_size,
                              hipStream_t stream) {
    const float* ctx    = (const float*)d_in[0];
    const int*   sid    = (const int*)  d_in[1];
    const float* eps    = (const float*)d_in[2];
    const float* w1     = (const float*)d_in[3];
    const float* b1     = (const float*)d_in[4];
    const float* w2     = (const float*)d_in[5];
    const float* b2     = (const float*)d_in[6];
    const float* subj_w = (const float*)d_in[7];
    const float* subj_b = (const float*)d_in[8];
    const float* lv_w   = (const float*)d_in[9];
    const float* lv_b   = (const float*)d_in[10];
    float* out = (float*)d_out;

    float* ws   = (float*)d_ws;
    float* pp   = ws + OFF_PP;
    float* p1   = ws + OFF_P1;
    float* p2   = ws + OFF_P2;
    float* hbuf = ws + OFF_H;
    float* mup  = ws + OFF_MUP;
    float* lvp  = ws + OFF_LVP;

    k_pool<<<dim3(BATCH, 16), 256, 0, stream>>>(ctx, pp);
    k_mlp1<<<dim3(4, 32, 2), 256, 0, stream>>>(pp, w1, p1);
    k_mlp2<<<dim3(4, 32, 2), 256, 0, stream>>>(p1, b1, w2, p2);
    k_red_bias<<<64, 256, 0, stream>>>(p2, b2, hbuf);
    k_head<<<768, 256, 0, stream>>>(hbuf, subj_w, lv_w, sid, mup, lvp);
    k_combine<<<512, 256, 0, stream>>>(mup, lvp, eps, subj_b, lv_b, sid, out);
}